// Round 6
// baseline (241.314 us; speedup 1.0000x reference)
//
#include <hip/hip_runtime.h>
#include <cstdint>

#define HW_ 4096

typedef __attribute__((ext_vector_type(8))) short bf16x8;
typedef __attribute__((ext_vector_type(4))) short bf16x4;
typedef __attribute__((ext_vector_type(4))) float f32x4;

static __device__ __forceinline__ unsigned short f2bf(float f) {
  unsigned u = __builtin_bit_cast(unsigned, f);
  u += 0x7FFF + ((u >> 16) & 1);
  return (unsigned short)(u >> 16);
}
static __device__ __forceinline__ float bf2f(unsigned short u) {
  return __builtin_bit_cast(float, (unsigned)u << 16);
}
static __device__ __forceinline__ float ldf(const float* p) { return *p; }
static __device__ __forceinline__ float ldf(const unsigned short* p) { return bf2f(*p); }

static __device__ __forceinline__ void gl_lds16(const unsigned short* g,
                                                unsigned short* s) {
  __builtin_amdgcn_global_load_lds(
      (const __attribute__((address_space(1))) unsigned int*)g,
      (__attribute__((address_space(3))) unsigned int*)s, 16, 0, 0);
}

// ---------- prep: weights fp32->bf16 (768x256 then 256x256) + bias_pre ----------
__global__ __launch_bounds__(256) void prep_kernel(
    const float* __restrict__ pw1, const float* __restrict__ pw2,
    unsigned short* __restrict__ wb, const float* __restrict__ btab,
    const int* __restrict__ relidx, float* __restrict__ bias_pre) {
  int idx = blockIdx.x * 256 + threadIdx.x;   // 786432
  if (idx < 262144) {
    wb[idx] = f2bf(idx < 196608 ? pw1[idx] : pw2[idx - 196608]);
  } else {
    int t = idx - 262144;                     // h*65536 + g*256 + j
    int j = t & 255, g = (t >> 8) & 255, h = t >> 16;
    bias_pre[t] = btab[relidx[g * 256 + j] * 8 + h] * 0.03125f;
  }
}

// ---------- fused depthwise 3x3 + pointwise MFMA GEMM ----------
// tile: 256 oc x 64 p (p-tile = one spatial row iy), BK=64, 4 waves.
// Per K-step: block computes its own dw B-tile (halo = rows iy-1..iy+1,
// horizontal taps via __shfl), writes swizzled LDS; W staged via gl_lds16
// with inverse-swizzled source. grid (64, OC/256, 8).
template <typename SRC, int OUT_BF16>
__global__ __launch_bounds__(256) void dwpw_kernel(
    const SRC* __restrict__ x, const float* __restrict__ dw9,
    const unsigned short* __restrict__ W, void* __restrict__ Yv, int OC) {
  __shared__ unsigned short smem[20480];   // 40 KB
  unsigned short* As = smem;               // 256x64 bf16 (32 KB), swizzled
  unsigned short* Bs = smem + 16384;       // 64x64 bf16 (8 KB), swizzled
  int iy  = blockIdx.x;                    // spatial row, p0 = iy*64
  int oc0 = blockIdx.y * 256;
  int b   = blockIdx.z;
  int tid = threadIdx.x;
  int lane = tid & 63;
  int wvu  = __builtin_amdgcn_readfirstlane(tid >> 6);  // wave idx (scalar)
  int lr = lane & 15, lg = lane >> 4;
  f32x4 acc[4][4] = {};
  const SRC* xrow = x + (size_t)b * 256 * HW_ + iy * 64 + lane;
  for (int kt = 0; kt < 4; ++kt) {
    int k0 = kt * 64;
    // --- A stage first (loads in flight during dw compute) ---
#pragma unroll
    for (int j = 0; j < 8; ++j) {
      int chunk = wvu * 8 + j;             // wave-uniform
      int row = chunk * 8 + (lane >> 3);
      int lcu = (lane & 7) ^ (row & 7);    // inverse-swizzled source
      gl_lds16(W + (size_t)(oc0 + row) * 256 + k0 + lcu * 8, &As[chunk * 512]);
    }
    // --- dw producer into Bs: thread = (px=lane, icg=wave), 16 ic each ---
    unsigned rr[8];
#pragma unroll
    for (int e = 0; e < 16; ++e) {
      int ic = k0 + wvu * 16 + e;
      const SRC* xp = xrow + (size_t)ic * HW_;
      const float* wp = dw9 + ic * 9;
      float v0 = (iy > 0) ? ldf(xp - 64) : 0.f;
      float v1 = ldf(xp);
      float v2 = (iy < 63) ? ldf(xp + 64) : 0.f;
      float l0 = __shfl(v0, lane - 1, 64), r0 = __shfl(v0, lane + 1, 64);
      float l1 = __shfl(v1, lane - 1, 64), r1 = __shfl(v1, lane + 1, 64);
      float l2 = __shfl(v2, lane - 1, 64), r2 = __shfl(v2, lane + 1, 64);
      if (lane == 0)  { l0 = 0.f; l1 = 0.f; l2 = 0.f; }
      if (lane == 63) { r0 = 0.f; r1 = 0.f; r2 = 0.f; }
      float a = l0 * wp[0] + v0 * wp[1] + r0 * wp[2]
              + l1 * wp[3] + v1 * wp[4] + r1 * wp[5]
              + l2 * wp[6] + v2 * wp[7] + r2 * wp[8];
      unsigned short hb = f2bf(a);
      if (e & 1) rr[e >> 1] |= (unsigned)hb << 16;
      else       rr[e >> 1] = (unsigned)hb;
    }
    {
      int u0 = (wvu * 2)     ^ (lane & 7);
      int u1 = (wvu * 2 + 1) ^ (lane & 7);
      uint4 t0 = {rr[0], rr[1], rr[2], rr[3]};
      uint4 t1 = {rr[4], rr[5], rr[6], rr[7]};
      *(uint4*)&Bs[lane * 64 + u0 * 8] = t0;
      *(uint4*)&Bs[lane * 64 + u1 * 8] = t1;
    }
    __syncthreads();
    // --- MFMA: wave owns oc band wvu*64..+63, all 64 p ---
#pragma unroll
    for (int ks = 0; ks < 2; ++ks) {
      int ku = ks * 4 + lg;
      bf16x8 af[4], bfr[4];
#pragma unroll
      for (int mi = 0; mi < 4; ++mi) {
        int row = wvu * 64 + mi * 16 + lr;
        af[mi] = *(const bf16x8*)&As[row * 64 + (ku ^ (row & 7)) * 8];
      }
#pragma unroll
      for (int ni = 0; ni < 4; ++ni) {
        int row = ni * 16 + lr;
        bfr[ni] = *(const bf16x8*)&Bs[row * 64 + (ku ^ (row & 7)) * 8];
      }
#pragma unroll
      for (int mi = 0; mi < 4; ++mi)
#pragma unroll
        for (int ni = 0; ni < 4; ++ni)
          acc[mi][ni] = __builtin_amdgcn_mfma_f32_16x16x32_bf16(
              af[mi], bfr[ni], acc[mi][ni], 0, 0, 0);
    }
    __syncthreads();
  }
  // D: col(l&15) = p-local (B rows), row((l>>4)*4+reg) = oc-local (A rows)
  if constexpr (OUT_BF16) {
    unsigned short* Cs = smem;             // 256 x 72 (36 KB), aliases As/Bs
#pragma unroll
    for (int mi = 0; mi < 4; ++mi)
#pragma unroll
      for (int ni = 0; ni < 4; ++ni)
#pragma unroll
        for (int r = 0; r < 4; ++r)
          Cs[(wvu * 64 + mi * 16 + lg * 4 + r) * 72 + ni * 16 + lr] =
              f2bf(acc[mi][ni][r]);
    __syncthreads();
    unsigned short* Yb = (unsigned short*)Yv + ((size_t)b * OC + oc0) * HW_ + iy * 64;
#pragma unroll
    for (int j = 0; j < 8; ++j) {
      int f = j * 256 + tid;
      int ocl = f >> 3, u = f & 7;
      uint4 pk = *(const uint4*)&Cs[ocl * 72 + u * 8];
      *(uint4*)(Yb + (size_t)ocl * HW_ + u * 8) = pk;
    }
  } else {
    float* Yb = (float*)Yv + ((size_t)b * OC + oc0) * HW_ + iy * 64;
#pragma unroll
    for (int mi = 0; mi < 4; ++mi)
#pragma unroll
      for (int ni = 0; ni < 4; ++ni)
#pragma unroll
        for (int r = 0; r < 4; ++r)
          Yb[(size_t)(wvu * 64 + mi * 16 + lg * 4 + r) * HW_ + ni * 16 + lr] =
              acc[mi][ni][r];
  }
}

// ---------- fused bilinear(64->16,ac) + heads + LN(k) -> kln, vfrag ----------
// 256 blocks x 256 thr; thread = jloc*4 + dg, handles 8 d = dg*8..dg*8+7
__global__ __launch_bounds__(256) void bilin_kvln_kernel(
    const unsigned short* __restrict__ qkvb, const float* __restrict__ g,
    const float* __restrict__ bb, unsigned short* __restrict__ kln,
    unsigned short* __restrict__ vfrag) {
  int bx = blockIdx.x;
  int bh = bx >> 2, jt = bx & 3;
  int h = bh & 7, b = bh >> 3;
  int tid = threadIdx.x;
  int jloc = tid >> 2, dg = tid & 3;
  int j = jt * 64 + jloc;
  int oy = j >> 4, ox = j & 15;
  const float s = 63.0f / 15.0f;
  float ys = oy * s, xf = ox * s;
  int y0 = (int)ys, x0 = (int)xf;
  int y1 = min(y0 + 1, 63), x1 = min(x0 + 1, 63);
  float wy = ys - (float)y0, wx = xf - (float)x0;
  float kv[8], vv[8];
  float sum = 0.f, sum2 = 0.f;
#pragma unroll
  for (int e = 0; e < 8; ++e) {
    int d = dg * 8 + e;
    const unsigned short* kp = qkvb + ((size_t)b * 768 + 256 + d * 8 + h) * HW_;
    const unsigned short* vp = qkvb + ((size_t)b * 768 + 512 + d * 8 + h) * HW_;
    float k00 = bf2f(kp[y0*64+x0]), k01 = bf2f(kp[y0*64+x1]);
    float k10 = bf2f(kp[y1*64+x0]), k11 = bf2f(kp[y1*64+x1]);
    float ktop = k00 * (1.f - wx) + k01 * wx;
    float kbot = k10 * (1.f - wx) + k11 * wx;
    kv[e] = ktop * (1.f - wy) + kbot * wy;
    float v00 = bf2f(vp[y0*64+x0]), v01 = bf2f(vp[y0*64+x1]);
    float v10 = bf2f(vp[y1*64+x0]), v11 = bf2f(vp[y1*64+x1]);
    float vtop = v00 * (1.f - wx) + v01 * wx;
    float vbot = v10 * (1.f - wx) + v11 * wx;
    vv[e] = vtop * (1.f - wy) + vbot * wy;
    sum += kv[e]; sum2 += kv[e] * kv[e];
  }
  sum  += __shfl_xor(sum, 1, 64);  sum  += __shfl_xor(sum, 2, 64);
  sum2 += __shfl_xor(sum2, 1, 64); sum2 += __shfl_xor(sum2, 2, 64);
  float mu = sum * (1.f / 32.f);
  float var = sum2 * (1.f / 32.f) - mu * mu;
  float inv = 1.0f / sqrtf(var + 1e-6f);
  unsigned r[4];
#pragma unroll
  for (int t = 0; t < 4; ++t) {
    int d0 = dg * 8 + 2 * t;
    float y0f = (kv[2*t]   - mu) * inv * g[h*32 + d0]     + bb[h*32 + d0];
    float y1f = (kv[2*t+1] - mu) * inv * g[h*32 + d0 + 1] + bb[h*32 + d0 + 1];
    r[t] = (unsigned)f2bf(y0f) | ((unsigned)f2bf(y1f) << 16);
  }
  uint4 pk = {r[0], r[1], r[2], r[3]};
  *(uint4*)(kln + ((size_t)bh * 256 + j) * 32 + dg * 8) = pk;
  // V in 16x16x16 A-fragment layout
  int c = j >> 4, gq = (j >> 2) & 3, ii = j & 3;
  unsigned short* vo = vfrag + (size_t)bh * 32 * 256;
#pragma unroll
  for (int e = 0; e < 8; ++e) {
    int d = dg * 8 + e;
    int dt = d >> 4, dr = d & 15;
    vo[(c * 2 + dt) * 256 + (gq * 16 + dr) * 4 + ii] = f2bf(vv[e]);
  }
}

// ---------------- MFMA attention with fused q-LayerNorm ----------------
__global__ __launch_bounds__(256) void attn_mfma_kernel(
    const unsigned short* __restrict__ qkvb, const float* __restrict__ gq,
    const float* __restrict__ bq, const unsigned short* __restrict__ kln,
    const unsigned short* __restrict__ vfrag, const float* __restrict__ bias_pre,
    float* __restrict__ attn_out, unsigned short* __restrict__ out_nchw) {
  int tile = blockIdx.x, h = blockIdx.y, b = blockIdx.z;
  int bh = b * 8 + h;
  int tid = threadIdx.x;
  int w = tid >> 6, l = tid & 63;
  int lr = l & 15, lg = l >> 4;
  int qbase = tile * 64 + w * 16;
  int q = qbase + lr;
  int iy = q >> 6, ix = q & 63;
  int g = (iy >> 2) * 16 + (ix >> 2);

  // fused q LayerNorm: lane loads its 8 raw q values, reduce across lg via shfl
  const unsigned short* qp = qkvb + ((size_t)b * 768 + h) * HW_ + q;
  float qv[8];
  float sum = 0.f, sum2 = 0.f;
#pragma unroll
  for (int e = 0; e < 8; ++e) {
    qv[e] = bf2f(qp[(size_t)((lg * 8 + e) * 8) * HW_]);
    sum += qv[e]; sum2 += qv[e] * qv[e];
  }
  sum  += __shfl_xor(sum, 16, 64);  sum  += __shfl_xor(sum, 32, 64);
  sum2 += __shfl_xor(sum2, 16, 64); sum2 += __shfl_xor(sum2, 32, 64);
  float mu = sum * (1.f / 32.f);
  float var = sum2 * (1.f / 32.f) - mu * mu;
  float inv = 1.0f / sqrtf(var + 1e-6f);
  bf16x8 qf;
#pragma unroll
  for (int e = 0; e < 8; ++e) {
    int d = lg * 8 + e;
    float y = (qv[e] - mu) * inv * gq[h * 32 + d] + bq[h * 32 + d];
    qf[e] = (short)f2bf(y);
  }

  const unsigned short* kbase = kln + (size_t)bh * 256 * 32 + lr * 32 + lg * 8;
  const unsigned short* vbase = vfrag + (size_t)bh * 32 * 256 + l * 4;
  const float* bbase = bias_pre + ((size_t)h * 256 + g) * 256 + lg * 4;
  float* abase = attn_out + ((size_t)bh * 4096 + q) * 256 + lg * 4;

  f32x4 z = {0.f, 0.f, 0.f, 0.f};
  f32x4 oacc0 = z, oacc1 = z;
#pragma unroll
  for (int c = 0; c < 16; ++c) {
    bf16x8 kf = *(const bf16x8*)(kbase + c * 16 * 32);
    f32x4 s = __builtin_amdgcn_mfma_f32_16x16x32_bf16(kf, qf, z, 0, 0, 0);
    f32x4 bias = *(const f32x4*)(bbase + c * 16);
    f32x4 t = s * 0.03125f + bias;
    __builtin_nontemporal_store(t, (f32x4*)(abase + c * 16));
    bf16x4 pb;
    pb[0] = (short)f2bf(t.x);
    pb[1] = (short)f2bf(t.y);
    pb[2] = (short)f2bf(t.z);
    pb[3] = (short)f2bf(t.w);
    bf16x4 va0 = *(const bf16x4*)(vbase + (c * 2 + 0) * 256);
    bf16x4 va1 = *(const bf16x4*)(vbase + (c * 2 + 1) * 256);
    oacc0 = __builtin_amdgcn_mfma_f32_16x16x16bf16_1k(va0, pb, oacc0, 0, 0, 0);
    oacc1 = __builtin_amdgcn_mfma_f32_16x16x16bf16_1k(va1, pb, oacc1, 0, 0, 0);
  }
  float ov[8] = {oacc0.x, oacc0.y, oacc0.z, oacc0.w,
                 oacc1.x, oacc1.y, oacc1.z, oacc1.w};
#pragma unroll
  for (int dt = 0; dt < 2; ++dt) {
#pragma unroll
    for (int r = 0; r < 4; ++r) {
      int d = dt * 16 + lg * 4 + r;
      int cc = d * 8 + h;
      out_nchw[((size_t)b * 256 + cc) * HW_ + qbase + lr] = f2bf(ov[dt * 4 + r]);
    }
  }
}

extern "C" void kernel_launch(void* const* d_in, const int* in_sizes, int n_in,
                              void* d_out, int out_size, void* d_ws, size_t ws_size,
                              hipStream_t stream) {
  const float* x      = (const float*)d_in[0];
  const float* qkv_dw = (const float*)d_in[1];
  const float* qkv_pw = (const float*)d_in[2];
  const float* out_dw = (const float*)d_in[3];
  const float* out_pw = (const float*)d_in[4];
  const float* gq     = (const float*)d_in[5];
  const float* bq     = (const float*)d_in[6];
  const float* gk     = (const float*)d_in[7];
  const float* bk     = (const float*)d_in[8];
  const float* btab   = (const float*)d_in[9];
  const int*   relidx = (const int*)d_in[10];

  float* out  = (float*)d_out;            // 8,388,608 floats
  float* attn = out + 8388608;            // 67,108,864 floats (268 MB)

  unsigned short* us = (unsigned short*)d_ws;
  unsigned short* onchwb = us;                    // 16.8 MB
  unsigned short* kln    = us + 8388608;          // 1 MB
  unsigned short* vfrag  = us + 8912896;          // 1 MB
  unsigned short* wbuf   = us + 9437184;          // 0.5 MB
  float* bias_pre = (float*)(us + 9699328);       // 2 MB
  unsigned short* qkvb   = us + 10747904;         // 50 MB  (total ~72 MB)

  prep_kernel<<<3072, 256, 0, stream>>>(qkv_pw, out_pw, wbuf, btab, relidx, bias_pre);
  dwpw_kernel<float, 1><<<dim3(64, 3, 8), 256, 0, stream>>>(
      x, qkv_dw, wbuf, qkvb, 768);
  bilin_kvln_kernel<<<256, 256, 0, stream>>>(qkvb, gk, bk, kln, vfrag);
  attn_mfma_kernel<<<dim3(64, 8, 8), 256, 0, stream>>>(qkvb, gq, bq, kln, vfrag,
                                                       bias_pre, attn, onchwb);
  dwpw_kernel<unsigned short, 0><<<dim3(64, 1, 8), 256, 0, stream>>>(
      onchwb, out_dw, wbuf + 196608, out, 256);
}

// Round 7
// 154.446 us; speedup vs baseline: 1.5624x; 1.5624x over previous
//
#include <hip/hip_runtime.h>
#include <cstdint>

#define HW_ 4096

typedef __attribute__((ext_vector_type(8))) short bf16x8;
typedef __attribute__((ext_vector_type(4))) short bf16x4;
typedef __attribute__((ext_vector_type(4))) float f32x4;

static __device__ __forceinline__ unsigned short f2bf(float f) {
  unsigned u = __builtin_bit_cast(unsigned, f);
  u += 0x7FFF + ((u >> 16) & 1);
  return (unsigned short)(u >> 16);
}
static __device__ __forceinline__ float bf2f(unsigned short u) {
  return __builtin_bit_cast(float, (unsigned)u << 16);
}
static __device__ __forceinline__ float ldf(const float* p) { return *p; }
static __device__ __forceinline__ float ldf(const unsigned short* p) { return bf2f(*p); }

static __device__ __forceinline__ void gl_lds16(const unsigned short* g,
                                                unsigned short* s) {
  __builtin_amdgcn_global_load_lds(
      (const __attribute__((address_space(1))) unsigned int*)g,
      (__attribute__((address_space(3))) unsigned int*)s, 16, 0, 0);
}

// ---------- fused depthwise 3x3 (pad1) + bf16 + transpose -> XT[b][p][c] ----------
// block: 64 px (one spatial row) x 64 c; horizontal taps via __shfl.
// DO_PREP: grid z==8 slice (256 blocks) converts pw weights + builds bias_pre.
template <typename T, int DO_PREP>
__global__ __launch_bounds__(256) void dwconv_t_kernel(
    const T* __restrict__ x, const float* __restrict__ w9,
    unsigned short* __restrict__ xT,
    const float* __restrict__ pw1, const float* __restrict__ pw2,
    unsigned short* __restrict__ wb, const float* __restrict__ btab,
    const int* __restrict__ relidx, float* __restrict__ bias_pre) {
  if (DO_PREP && blockIdx.z == 8) {
    int idx0 = (blockIdx.y * 64 + blockIdx.x) * 256 + threadIdx.x;  // 0..65535
#pragma unroll
    for (int k = 0; k < 12; ++k) {
      int idx = idx0 + k * 65536;                 // 786432 items total
      if (idx < 262144) {
        wb[idx] = f2bf(idx < 196608 ? pw1[idx] : pw2[idx - 196608]);
      } else {
        int t = idx - 262144;                     // h*65536 + g*256 + j
        int j = t & 255, g = (t >> 8) & 255, h = t >> 16;
        bias_pre[t] = btab[relidx[g * 256 + j] * 8 + h] * 0.03125f;
      }
    }
    return;
  }
  __shared__ unsigned short lds_t[64][66];
  int iy = blockIdx.x;
  int cg = blockIdx.y;
  int b  = blockIdx.z;
  int tid = threadIdx.x;
  int px  = tid & 63;                             // lane == px
  int cl0 = (tid >> 6) * 16;
  const T* xrow = x + (size_t)b * 256 * HW_ + iy * 64 + px;
#pragma unroll 4
  for (int e = 0; e < 16; ++e) {
    int c = cg * 64 + cl0 + e;
    const T* xp = xrow + (size_t)c * HW_;
    const float* wp = w9 + c * 9;
    float v0 = (iy > 0)  ? ldf(xp - 64) : 0.f;
    float v1 = ldf(xp);
    float v2 = (iy < 63) ? ldf(xp + 64) : 0.f;
    float l0 = __shfl(v0, px - 1, 64), r0 = __shfl(v0, px + 1, 64);
    float l1 = __shfl(v1, px - 1, 64), r1 = __shfl(v1, px + 1, 64);
    float l2 = __shfl(v2, px - 1, 64), r2 = __shfl(v2, px + 1, 64);
    if (px == 0)  { l0 = 0.f; l1 = 0.f; l2 = 0.f; }
    if (px == 63) { r0 = 0.f; r1 = 0.f; r2 = 0.f; }
    float acc = l0 * wp[0] + v0 * wp[1] + r0 * wp[2]
              + l1 * wp[3] + v1 * wp[4] + r1 * wp[5]
              + l2 * wp[6] + v2 * wp[7] + r2 * wp[8];
    lds_t[cl0 + e][px] = f2bf(acc);
  }
  __syncthreads();
#pragma unroll
  for (int j = 0; j < 2; ++j) {
    int flat = tid + j * 256;
    int rpx = flat >> 3, cseg = flat & 7;
    unsigned v0 = (unsigned)lds_t[cseg*8+0][rpx] | ((unsigned)lds_t[cseg*8+1][rpx] << 16);
    unsigned v1 = (unsigned)lds_t[cseg*8+2][rpx] | ((unsigned)lds_t[cseg*8+3][rpx] << 16);
    unsigned v2 = (unsigned)lds_t[cseg*8+4][rpx] | ((unsigned)lds_t[cseg*8+5][rpx] << 16);
    unsigned v3 = (unsigned)lds_t[cseg*8+6][rpx] | ((unsigned)lds_t[cseg*8+7][rpx] << 16);
    uint4 pk = {v0, v1, v2, v3};
    *(uint4*)(xT + ((size_t)b * 4096 + iy * 64 + rpx) * 256 + cg * 64 + cseg * 8) = pk;
  }
}

// ---------- pointwise conv as bf16 MFMA GEMM; bf16 out via LDS-staged store ----------
template <int OUT_BF16>
__global__ __launch_bounds__(256) void pwconv_mfma_kernel(
    const unsigned short* __restrict__ XT, const unsigned short* __restrict__ W,
    void* __restrict__ Yv, int OC) {
  __shared__ unsigned short As[128 * 64];
  __shared__ unsigned short Bs[128 * 64];
  int b = blockIdx.z, oc0 = blockIdx.y * 128, p0 = blockIdx.x * 128;
  int tid = threadIdx.x;
  int w = tid >> 6, l = tid & 63;
  int wm = w >> 1, wn = w & 1;
  int lr = l & 15, lg = l >> 4;
  const unsigned short* Wp = W + (size_t)oc0 * 256;
  const unsigned short* Xp = XT + ((size_t)b * 4096 + p0) * 256;
  f32x4 acc[4][4] = {};
  for (int kt = 0; kt < 4; ++kt) {
    int k0 = kt * 64;
#pragma unroll
    for (int j = 0; j < 4; ++j) {
      int chunk = w * 4 + j;            // wave-uniform
      int row = chunk * 8 + (l >> 3);
      int lcu = (l & 7) ^ (row & 7);    // inverse-swizzled source column
      gl_lds16(Wp + (size_t)row * 256 + k0 + lcu * 8, &As[chunk * 512]);
      gl_lds16(Xp + (size_t)row * 256 + k0 + lcu * 8, &Bs[chunk * 512]);
    }
    __syncthreads();
#pragma unroll
    for (int ks = 0; ks < 2; ++ks) {
      bf16x8 af[4], bfr[4];
      int ku = ks * 4 + lg;
#pragma unroll
      for (int mi = 0; mi < 4; ++mi) {
        int row = wm * 64 + mi * 16 + lr;
        af[mi] = *(const bf16x8*)&As[row * 64 + (ku ^ (row & 7)) * 8];
      }
#pragma unroll
      for (int ni = 0; ni < 4; ++ni) {
        int row = wn * 64 + ni * 16 + lr;
        bfr[ni] = *(const bf16x8*)&Bs[row * 64 + (ku ^ (row & 7)) * 8];
      }
#pragma unroll
      for (int mi = 0; mi < 4; ++mi)
#pragma unroll
        for (int ni = 0; ni < 4; ++ni)
          acc[mi][ni] = __builtin_amdgcn_mfma_f32_16x16x32_bf16(
              af[mi], bfr[ni], acc[mi][ni], 0, 0, 0);
    }
    __syncthreads();
  }
  // D: col(l&15) = p-local, row((l>>4)*4+reg) = oc-local
  if constexpr (OUT_BF16) {
    __shared__ unsigned short Cs[128][136];
#pragma unroll
    for (int mi = 0; mi < 4; ++mi)
#pragma unroll
      for (int ni = 0; ni < 4; ++ni)
#pragma unroll
        for (int r = 0; r < 4; ++r)
          Cs[wm * 64 + mi * 16 + lg * 4 + r][wn * 64 + ni * 16 + lr] =
              f2bf(acc[mi][ni][r]);
    __syncthreads();
    unsigned short* Yb = (unsigned short*)Yv + (size_t)b * OC * HW_;
    int pc = tid & 15, ocr = tid >> 4;
#pragma unroll
    for (int it = 0; it < 8; ++it) {
      int oc = it * 16 + ocr;
      uint4 pk = *(const uint4*)&Cs[oc][pc * 8];
      *(uint4*)(Yb + (size_t)(oc0 + oc) * HW_ + p0 + pc * 8) = pk;
    }
  } else {
    float* Yb = (float*)Yv + (size_t)b * OC * HW_;
#pragma unroll
    for (int mi = 0; mi < 4; ++mi)
#pragma unroll
      for (int ni = 0; ni < 4; ++ni)
#pragma unroll
        for (int r = 0; r < 4; ++r) {
          int oc = oc0 + wm * 64 + mi * 16 + lg * 4 + r;
          int p  = p0 + wn * 64 + ni * 16 + lr;
          Yb[(size_t)oc * HW_ + p] = acc[mi][ni][r];
        }
  }
}

// ---------- fused bilinear(64->16,ac) + heads + LN(k) -> kln, vfrag ----------
// 256 blocks x 256 thr; thread = jloc*4 + dg, handles 8 d = dg*8..dg*8+7
__global__ __launch_bounds__(256) void bilin_kvln_kernel(
    const unsigned short* __restrict__ qkvb, const float* __restrict__ g,
    const float* __restrict__ bb, unsigned short* __restrict__ kln,
    unsigned short* __restrict__ vfrag) {
  int bx = blockIdx.x;
  int bh = bx >> 2, jt = bx & 3;
  int h = bh & 7, b = bh >> 3;
  int tid = threadIdx.x;
  int jloc = tid >> 2, dg = tid & 3;
  int j = jt * 64 + jloc;
  int oy = j >> 4, ox = j & 15;
  const float s = 63.0f / 15.0f;
  float ys = oy * s, xf = ox * s;
  int y0 = (int)ys, x0 = (int)xf;
  int y1 = min(y0 + 1, 63), x1 = min(x0 + 1, 63);
  float wy = ys - (float)y0, wx = xf - (float)x0;
  float kv[8], vv[8];
  float sum = 0.f, sum2 = 0.f;
#pragma unroll
  for (int e = 0; e < 8; ++e) {
    int d = dg * 8 + e;
    const unsigned short* kp = qkvb + ((size_t)b * 768 + 256 + d * 8 + h) * HW_;
    const unsigned short* vp = qkvb + ((size_t)b * 768 + 512 + d * 8 + h) * HW_;
    float k00 = bf2f(kp[y0*64+x0]), k01 = bf2f(kp[y0*64+x1]);
    float k10 = bf2f(kp[y1*64+x0]), k11 = bf2f(kp[y1*64+x1]);
    float ktop = k00 * (1.f - wx) + k01 * wx;
    float kbot = k10 * (1.f - wx) + k11 * wx;
    kv[e] = ktop * (1.f - wy) + kbot * wy;
    float v00 = bf2f(vp[y0*64+x0]), v01 = bf2f(vp[y0*64+x1]);
    float v10 = bf2f(vp[y1*64+x0]), v11 = bf2f(vp[y1*64+x1]);
    float vtop = v00 * (1.f - wx) + v01 * wx;
    float vbot = v10 * (1.f - wx) + v11 * wx;
    vv[e] = vtop * (1.f - wy) + vbot * wy;
    sum += kv[e]; sum2 += kv[e] * kv[e];
  }
  sum  += __shfl_xor(sum, 1, 64);  sum  += __shfl_xor(sum, 2, 64);
  sum2 += __shfl_xor(sum2, 1, 64); sum2 += __shfl_xor(sum2, 2, 64);
  float mu = sum * (1.f / 32.f);
  float var = sum2 * (1.f / 32.f) - mu * mu;
  float inv = 1.0f / sqrtf(var + 1e-6f);
  unsigned r[4];
#pragma unroll
  for (int t = 0; t < 4; ++t) {
    int d0 = dg * 8 + 2 * t;
    float y0f = (kv[2*t]   - mu) * inv * g[h*32 + d0]     + bb[h*32 + d0];
    float y1f = (kv[2*t+1] - mu) * inv * g[h*32 + d0 + 1] + bb[h*32 + d0 + 1];
    r[t] = (unsigned)f2bf(y0f) | ((unsigned)f2bf(y1f) << 16);
  }
  uint4 pk = {r[0], r[1], r[2], r[3]};
  *(uint4*)(kln + ((size_t)bh * 256 + j) * 32 + dg * 8) = pk;
  // V in 16x16x16 A-fragment layout
  int c = j >> 4, gq = (j >> 2) & 3, ii = j & 3;
  unsigned short* vo = vfrag + (size_t)bh * 32 * 256;
#pragma unroll
  for (int e = 0; e < 8; ++e) {
    int d = dg * 8 + e;
    int dt = d >> 4, dr = d & 15;
    vo[(c * 2 + dt) * 256 + (gq * 16 + dr) * 4 + ii] = f2bf(vv[e]);
  }
}

// ---------------- MFMA attention with fused q-LayerNorm ----------------
__global__ __launch_bounds__(256) void attn_mfma_kernel(
    const unsigned short* __restrict__ qkvb, const float* __restrict__ gq,
    const float* __restrict__ bq, const unsigned short* __restrict__ kln,
    const unsigned short* __restrict__ vfrag, const float* __restrict__ bias_pre,
    float* __restrict__ attn_out, unsigned short* __restrict__ out_nchw) {
  int tile = blockIdx.x, h = blockIdx.y, b = blockIdx.z;
  int bh = b * 8 + h;
  int tid = threadIdx.x;
  int w = tid >> 6, l = tid & 63;
  int lr = l & 15, lg = l >> 4;
  int qbase = tile * 64 + w * 16;
  int q = qbase + lr;
  int iy = q >> 6, ix = q & 63;
  int g = (iy >> 2) * 16 + (ix >> 2);

  // fused q LayerNorm: lane loads its 8 raw q values, reduce across lg via shfl
  const unsigned short* qp = qkvb + ((size_t)b * 768 + h) * HW_ + q;
  float qv[8];
  float sum = 0.f, sum2 = 0.f;
#pragma unroll
  for (int e = 0; e < 8; ++e) {
    qv[e] = bf2f(qp[(size_t)((lg * 8 + e) * 8) * HW_]);
    sum += qv[e]; sum2 += qv[e] * qv[e];
  }
  sum  += __shfl_xor(sum, 16, 64);  sum  += __shfl_xor(sum, 32, 64);
  sum2 += __shfl_xor(sum2, 16, 64); sum2 += __shfl_xor(sum2, 32, 64);
  float mu = sum * (1.f / 32.f);
  float var = sum2 * (1.f / 32.f) - mu * mu;
  float inv = 1.0f / sqrtf(var + 1e-6f);
  bf16x8 qf;
#pragma unroll
  for (int e = 0; e < 8; ++e) {
    int d = lg * 8 + e;
    float y = (qv[e] - mu) * inv * gq[h * 32 + d] + bq[h * 32 + d];
    qf[e] = (short)f2bf(y);
  }

  const unsigned short* kbase = kln + (size_t)bh * 256 * 32 + lr * 32 + lg * 8;
  const unsigned short* vbase = vfrag + (size_t)bh * 32 * 256 + l * 4;
  const float* bbase = bias_pre + ((size_t)h * 256 + g) * 256 + lg * 4;
  float* abase = attn_out + ((size_t)bh * 4096 + q) * 256 + lg * 4;

  f32x4 z = {0.f, 0.f, 0.f, 0.f};
  f32x4 oacc0 = z, oacc1 = z;
#pragma unroll
  for (int c = 0; c < 16; ++c) {
    bf16x8 kf = *(const bf16x8*)(kbase + c * 16 * 32);
    f32x4 s = __builtin_amdgcn_mfma_f32_16x16x32_bf16(kf, qf, z, 0, 0, 0);
    f32x4 bias = *(const f32x4*)(bbase + c * 16);
    f32x4 t = s * 0.03125f + bias;
    __builtin_nontemporal_store(t, (f32x4*)(abase + c * 16));
    bf16x4 pb;
    pb[0] = (short)f2bf(t.x);
    pb[1] = (short)f2bf(t.y);
    pb[2] = (short)f2bf(t.z);
    pb[3] = (short)f2bf(t.w);
    bf16x4 va0 = *(const bf16x4*)(vbase + (c * 2 + 0) * 256);
    bf16x4 va1 = *(const bf16x4*)(vbase + (c * 2 + 1) * 256);
    oacc0 = __builtin_amdgcn_mfma_f32_16x16x16bf16_1k(va0, pb, oacc0, 0, 0, 0);
    oacc1 = __builtin_amdgcn_mfma_f32_16x16x16bf16_1k(va1, pb, oacc1, 0, 0, 0);
  }
  float ov[8] = {oacc0.x, oacc0.y, oacc0.z, oacc0.w,
                 oacc1.x, oacc1.y, oacc1.z, oacc1.w};
#pragma unroll
  for (int dt = 0; dt < 2; ++dt) {
#pragma unroll
    for (int r = 0; r < 4; ++r) {
      int d = dt * 16 + lg * 4 + r;
      int cc = d * 8 + h;
      out_nchw[((size_t)b * 256 + cc) * HW_ + qbase + lr] = f2bf(ov[dt * 4 + r]);
    }
  }
}

extern "C" void kernel_launch(void* const* d_in, const int* in_sizes, int n_in,
                              void* d_out, int out_size, void* d_ws, size_t ws_size,
                              hipStream_t stream) {
  const float* x      = (const float*)d_in[0];
  const float* qkv_dw = (const float*)d_in[1];
  const float* qkv_pw = (const float*)d_in[2];
  const float* out_dw = (const float*)d_in[3];
  const float* out_pw = (const float*)d_in[4];
  const float* gq     = (const float*)d_in[5];
  const float* bq     = (const float*)d_in[6];
  const float* gk     = (const float*)d_in[7];
  const float* bk     = (const float*)d_in[8];
  const float* btab   = (const float*)d_in[9];
  const int*   relidx = (const int*)d_in[10];

  float* out  = (float*)d_out;            // 8,388,608 floats
  float* attn = out + 8388608;            // 67,108,864 floats (268 MB)

  unsigned short* us = (unsigned short*)d_ws;
  unsigned short* xT1    = us;                    // 16.8 MB
  unsigned short* xT2    = us + 8388608;          // 16.8 MB
  unsigned short* onchwb = us + 16777216;         // 16.8 MB
  unsigned short* kln    = us + 25165824;         // 1 MB
  unsigned short* vfrag  = us + 25690112;         // 1 MB
  unsigned short* wbuf   = us + 26214400;         // 0.5 MB
  float* bias_pre = (float*)(us + 26476544);      // 2 MB
  unsigned short* qkvb   = us + 27525120;         // 50 MB  (total ~105 MB)

  dwconv_t_kernel<float, 1><<<dim3(64, 4, 9), 256, 0, stream>>>(
      x, qkv_dw, xT1, qkv_pw, out_pw, wbuf, btab, relidx, bias_pre);
  pwconv_mfma_kernel<1><<<dim3(32, 6, 8), 256, 0, stream>>>(xT1, wbuf, qkvb, 768);
  bilin_kvln_kernel<<<256, 256, 0, stream>>>(qkvb, gk, bk, kln, vfrag);
  attn_mfma_kernel<<<dim3(64, 8, 8), 256, 0, stream>>>(qkvb, gq, bq, kln, vfrag,
                                                       bias_pre, attn, onchwb);
  dwconv_t_kernel<unsigned short, 0><<<dim3(64, 4, 8), 256, 0, stream>>>(
      onchwb, out_dw, xT2, nullptr, nullptr, nullptr, nullptr, nullptr, nullptr);
  pwconv_mfma_kernel<0><<<dim3(32, 2, 8), 256, 0, stream>>>(xT2, wbuf + 196608, out, 256);
}